// Round 6
// baseline (143.073 us; speedup 1.0000x reference)
//
#include <hip/hip_runtime.h>

#define SIGMA 0.5f
#define BB 32
#define NVV 6890
#define NFF 13776
#define MAXC 8
#define NCC (NFF * MAXC)                 // 110208 pairs per batch

// per-(batch,face) record, fp16: c[3], n[3], v0[3], v1[3], v2[3], pad -> 16 halves = 32B
#define REC_HALFS 16
#define REC_BYTES ((size_t)BB * NFF * REC_HALFS * sizeof(_Float16))   // ~14.1 MB

// pair grid: x = batch (32) -> XCD b%8 (x-major dispatch, 32%8==0); y = slot.
// 2 pairs per thread -> 512 pairs per 256-thread block.
#define PAIRS_PER_BLOCK 512
#define SLOTS2 ((NCC + PAIRS_PER_BLOCK - 1) / PAIRS_PER_BLOCK)        // 216
#define NPART (BB * SLOTS2)                                           // 6912

// face kernel split: grid (32, FSPLIT), FPB faces per block
#define FSPLIT 24
#define FPB (NFF / FSPLIT)               // 574 (exact: 574*24 = 13776)

typedef int v4i __attribute__((ext_vector_type(4)));

union RecU {
    uint4    u[2];
    _Float16 h[16];
};

__device__ __forceinline__ float3 loadv3(const float* __restrict__ p) {
    return make_float3(p[0], p[1], p[2]);
}

// ---------------- phase 1: LDS-staged fp16 face records ----------------
// Each block stages its batch's full vertex set (fp16, 41.3 KB) into LDS with
// coalesced float2 loads, then computes FPB face records from LDS (DS pipe,
// off the VMEM texture-address path).
__global__ __launch_bounds__(256) void face_lds_kernel(
    const float* __restrict__ vertices,   // [B, NV, 3]
    const int*   __restrict__ faces,      // [NF, 3]
    uint4*       __restrict__ rec)        // [B*NF][2]
{
    __shared__ _Float16 sv[NVV * 3];      // 41,340 B

    const int b  = blockIdx.x;            // batch -> XCD b%8 (matches pair consumers)
    const int s  = blockIdx.y;
    const int t  = threadIdx.x;

    // stage: 20670 floats = 10335 float2, coalesced
    const float2* vb2 = (const float2*)(vertices + (size_t)b * (NVV * 3));
    uint* svu = (uint*)sv;
    for (int j = t; j < (NVV * 3) / 2; j += 256) {
        float2 v = vb2[j];
        union { uint u; _Float16 h[2]; } pk;
        pk.h[0] = (_Float16)v.x;
        pk.h[1] = (_Float16)v.y;
        svu[j] = pk.u;
    }
    __syncthreads();

    const int f0 = s * FPB;
    for (int r = t; r < FPB; r += 256) {
        const int f = f0 + r;
        const int i0 = faces[f * 3 + 0];
        const int i1 = faces[f * 3 + 1];
        const int i2 = faces[f * 3 + 2];

        float v0x = (float)sv[i0*3+0], v0y = (float)sv[i0*3+1], v0z = (float)sv[i0*3+2];
        float v1x = (float)sv[i1*3+0], v1y = (float)sv[i1*3+1], v1z = (float)sv[i1*3+2];
        float v2x = (float)sv[i2*3+0], v2y = (float)sv[i2*3+1], v2z = (float)sv[i2*3+2];

        const float third = 1.0f / 3.0f;
        float cx = (v0x + v1x + v2x) * third;
        float cy = (v0y + v1y + v2y) * third;
        float cz = (v0z + v1z + v2z) * third;

        float e1x = v1x - v0x, e1y = v1y - v0y, e1z = v1z - v0z;
        float e2x = v2x - v0x, e2y = v2y - v0y, e2z = v2z - v0z;
        float nx = e1y * e2z - e1z * e2y;
        float ny = e1z * e2x - e1x * e2z;
        float nz = e1x * e2y - e1y * e2x;
        float inv = 1.0f / (sqrtf(nx * nx + ny * ny + nz * nz) + 1e-8f);
        nx *= inv; ny *= inv; nz *= inv;

        RecU rc;
        rc.h[0]  = (_Float16)cx;  rc.h[1]  = (_Float16)cy;  rc.h[2]  = (_Float16)cz;
        rc.h[3]  = (_Float16)nx;  rc.h[4]  = (_Float16)ny;  rc.h[5]  = (_Float16)nz;
        rc.h[6]  = (_Float16)v0x; rc.h[7]  = (_Float16)v0y; rc.h[8]  = (_Float16)v0z;
        rc.h[9]  = (_Float16)v1x; rc.h[10] = (_Float16)v1y; rc.h[11] = (_Float16)v1z;
        rc.h[12] = (_Float16)v2x; rc.h[13] = (_Float16)v2y; rc.h[14] = (_Float16)v2z;
        rc.h[15] = (_Float16)0.0f;

        uint4* dst = rec + ((size_t)b * NFF + f) * 2;
        dst[0] = rc.u[0];
        dst[1] = rc.u[1];
    }
}

// one side: query verts (rec halves 6..14) in cone field (c, n from rec halves 0..5)
__device__ __forceinline__ float penSide(const RecU& C, const RecU& Q) {
    float cx = (float)C.h[0], cy = (float)C.h[1], cz = (float)C.h[2];
    float nx = (float)C.h[3], ny = (float)C.h[4], nz = (float)C.h[5];
    float pen = 0.0f;
#pragma unroll
    for (int v = 0; v < 3; ++v) {
        float dx = (float)Q.h[6 + 3 * v + 0] - cx;
        float dy = (float)Q.h[6 + 3 * v + 1] - cy;
        float dz = (float)Q.h[6 + 3 * v + 2] - cz;
        float h = dx * nx + dy * ny + dz * nz;
        float r = sqrtf(dx * dx + dy * dy + dz * dz);
        float phi = fmaxf(SIGMA - r, 0.0f);
        pen += (h < 0.0f) ? phi * h * h : 0.0f;
    }
    return pen;
}

// ---------------- phase 2: 2 pairs/thread, branchless hoisted loads ----------
__global__ __launch_bounds__(256) void pair_kernel(
    const uint4* __restrict__ rec,        // [B*NF][2]
    const int*   __restrict__ cidx,       // [B, NC, 2]
    float*       __restrict__ partials)   // [NPART]
{
    const int b    = blockIdx.x;          // batch -> XCD b%8
    const int slot = blockIdx.y;
    const int base = slot * PAIRS_PER_BLOCK + threadIdx.x * 2;  // pairs {base, base+1}
    float pen = 0.0f;

    if (base < NCC) {                     // NCC even, base even -> covers base+1
        const v4i* c4 = (const v4i*)(cidx + (size_t)b * NCC * 2)
                        + ((size_t)slot * 256 + threadIdx.x);
        v4i pr = __builtin_nontemporal_load(c4);   // {r0,i0,r1,i1}

        const bool valid0 = pr.x >= 0;
        const bool valid1 = pr.z >= 0;
        int fi[4] = { pr.x < 0 ? 0 : pr.x, pr.y < 0 ? 0 : pr.y,
                      pr.z < 0 ? 0 : pr.z, pr.w < 0 ? 0 : pr.w };

        // hoist all 8 gather loads (4 records x 2 uint4) before any compute
        RecU R[4];
        const uint4* rbase = rec + (size_t)b * NFF * 2;
#pragma unroll
        for (int k = 0; k < 4; ++k) {
            const uint4* rp = rbase + (size_t)fi[k] * 2;
            R[k].u[0] = rp[0];
            R[k].u[1] = rp[1];
        }

        float p0 = penSide(R[0], R[1]) + penSide(R[1], R[0]);
        float p1 = penSide(R[2], R[3]) + penSide(R[3], R[2]);
        pen = (valid0 ? p0 : 0.0f) + (valid1 ? p1 : 0.0f);
    }

    // wave (64-lane) shuffle reduce
#pragma unroll
    for (int off = 32; off > 0; off >>= 1)
        pen += __shfl_down(pen, off, 64);

    __shared__ float smem[4];
    const int lane = threadIdx.x & 63;
    const int wv   = threadIdx.x >> 6;
    if (lane == 0) smem[wv] = pen;
    __syncthreads();
    if (threadIdx.x == 0)
        partials[(size_t)b * SLOTS2 + slot] = smem[0] + smem[1] + smem[2] + smem[3];
}

// ---------------- phase 3: fold partials, apply weight/B ----------------
__global__ __launch_bounds__(1024) void reduce_kernel(
    const float* __restrict__ partials,
    const float* __restrict__ weight,
    float*       __restrict__ out)
{
    float s = 0.0f;
    for (int i = threadIdx.x; i < NPART; i += 1024)
        s += partials[i];
#pragma unroll
    for (int off = 32; off > 0; off >>= 1)
        s += __shfl_down(s, off, 64);

    __shared__ float smem[16];
    const int lane = threadIdx.x & 63;
    const int wv   = threadIdx.x >> 6;
    if (lane == 0) smem[wv] = s;
    __syncthreads();
    if (threadIdx.x == 0) {
        float t = 0.0f;
#pragma unroll
        for (int w = 0; w < 16; ++w) t += smem[w];
        out[0] = t * weight[0] * (1.0f / (float)BB);
    }
}

// ---------------- fallback: direct per-pair with atomics (tiny ws) --------
__global__ void init_kernel(float* __restrict__ accum) { accum[0] = 0.0f; }

__device__ __forceinline__ float conePen(float3 a0, float3 a1, float3 a2,
                                         float3 q0, float3 q1, float3 q2) {
    const float third = 1.0f / 3.0f;
    float cx = (a0.x + a1.x + a2.x) * third;
    float cy = (a0.y + a1.y + a2.y) * third;
    float cz = (a0.z + a1.z + a2.z) * third;
    float e1x = a1.x - a0.x, e1y = a1.y - a0.y, e1z = a1.z - a0.z;
    float e2x = a2.x - a0.x, e2y = a2.y - a0.y, e2z = a2.z - a0.z;
    float nx = e1y * e2z - e1z * e2y;
    float ny = e1z * e2x - e1x * e2z;
    float nz = e1x * e2y - e1y * e2x;
    float inv = 1.0f / (sqrtf(nx * nx + ny * ny + nz * nz) + 1e-8f);
    nx *= inv; ny *= inv; nz *= inv;
    float3 q[3] = {q0, q1, q2};
    float pen = 0.0f;
#pragma unroll
    for (int v = 0; v < 3; ++v) {
        float dx = q[v].x - cx, dy = q[v].y - cy, dz = q[v].z - cz;
        float h = dx * nx + dy * ny + dz * nz;
        float r = sqrtf(dx * dx + dy * dy + dz * dz);
        float phi = fmaxf(SIGMA - r, 0.0f);
        pen += (h < 0.0f) ? phi * h * h : 0.0f;
    }
    return pen;
}

__global__ __launch_bounds__(256) void pen_direct(
    const float* __restrict__ vertices, const int* __restrict__ faces,
    const int2* __restrict__ cidx, float* __restrict__ accum)
{
    const int i = blockIdx.x * blockDim.x + threadIdx.x;
    float pen = 0.0f;
    if (i < BB * NCC) {
        const int b = i / NCC;
        const int2 pr = cidx[i];
        if (pr.x >= 0) {
            const int f0 = pr.x;
            const int f1 = pr.y < 0 ? 0 : pr.y;
            const float* vb = vertices + (size_t)b * (NVV * 3);
            float3 a0 = loadv3(vb + (size_t)faces[f0*3+0] * 3);
            float3 a1 = loadv3(vb + (size_t)faces[f0*3+1] * 3);
            float3 a2 = loadv3(vb + (size_t)faces[f0*3+2] * 3);
            float3 b0 = loadv3(vb + (size_t)faces[f1*3+0] * 3);
            float3 b1 = loadv3(vb + (size_t)faces[f1*3+1] * 3);
            float3 b2 = loadv3(vb + (size_t)faces[f1*3+2] * 3);
            pen = conePen(a0,a1,a2,b0,b1,b2) + conePen(b0,b1,b2,a0,a1,a2);
        }
    }
#pragma unroll
    for (int off = 32; off > 0; off >>= 1)
        pen += __shfl_down(pen, off, 64);
    __shared__ float smem[4];
    const int lane = threadIdx.x & 63;
    const int wv   = threadIdx.x >> 6;
    if (lane == 0) smem[wv] = pen;
    __syncthreads();
    if (threadIdx.x == 0)
        atomicAdd(accum, smem[0] + smem[1] + smem[2] + smem[3]);
}

__global__ void fin_kernel(const float* __restrict__ accum,
                           const float* __restrict__ weight,
                           float* __restrict__ out)
{
    out[0] = accum[0] * weight[0] * (1.0f / (float)BB);
}

extern "C" void kernel_launch(void* const* d_in, const int* in_sizes, int n_in,
                              void* d_out, int out_size, void* d_ws, size_t ws_size,
                              hipStream_t stream) {
    const float* vertices = (const float*)d_in[4];
    const float* weight   = (const float*)d_in[5];
    const int*   faces    = (const int*)d_in[6];
    const int*   cidx     = (const int*)d_in[7];
    float* out = (float*)d_out;

    if (ws_size >= REC_BYTES + NPART * sizeof(float) + 256) {
        uint4* rec      = (uint4*)d_ws;
        float* partials = (float*)((char*)d_ws + REC_BYTES);

        face_lds_kernel<<<dim3(BB, FSPLIT), dim3(256), 0, stream>>>(
            vertices, faces, rec);
        pair_kernel<<<dim3(BB, SLOTS2), dim3(256), 0, stream>>>(rec, cidx, partials);
        reduce_kernel<<<dim3(1), dim3(1024), 0, stream>>>(partials, weight, out);
    } else {
        float* accum = (float*)d_ws;
        const int totalPairs = BB * NCC;
        init_kernel<<<dim3(1), dim3(1), 0, stream>>>(accum);
        pen_direct<<<dim3((totalPairs + 255) / 256), dim3(256), 0, stream>>>(
            vertices, faces, (const int2*)cidx, accum);
        fin_kernel<<<dim3(1), dim3(1), 0, stream>>>(accum, weight, out);
    }
}

// Round 7
// 135.906 us; speedup vs baseline: 1.0527x; 1.0527x over previous
//
#include <hip/hip_runtime.h>

#define SIGMA 0.5f
#define BB 32
#define NVV 6890
#define NFF 13776
#define MAXC 8
#define NCC (NFF * MAXC)                 // 110208 pairs per batch

// per-(batch,face) record, fp16: c[3], n[3], v0[3], v1[3], v2[3], pad -> 16 halves = 32B
#define REC_HALFS 16
#define REC_BYTES ((size_t)BB * NFF * REC_HALFS * sizeof(_Float16))   // ~14.1 MB

// pair grid: x = batch (32) -> XCD b%8 (x-major dispatch, 32%8==0); y = slot.
// 2 pairs per thread -> 512 pairs per 256-thread block, one partial per WAVE.
#define PAIRS_PER_BLOCK 512
#define SLOTS2 ((NCC + PAIRS_PER_BLOCK - 1) / PAIRS_PER_BLOCK)        // 216
#define NPART (BB * SLOTS2 * 4)                                       // 27648 wave partials

typedef int v4i __attribute__((ext_vector_type(4)));

union RecU {
    uint4    u[2];
    _Float16 h[16];
};

__device__ __forceinline__ float3 loadv3(const float* __restrict__ p) {
    return make_float3(p[0], p[1], p[2]);
}

// ---------------- phase 1: per-(b,f) fp16 face records (R4 version) ----------
__global__ __launch_bounds__(256) void face_kernel(
    const float* __restrict__ vertices,   // [B, NV, 3]
    const int*   __restrict__ faces,      // [NF, 3]
    uint4*       __restrict__ rec)        // [B*NF][2]
{
    const int i = blockIdx.x * blockDim.x + threadIdx.x;
    if (i >= BB * NFF) return;
    const int b = i / NFF;
    const int f = i - b * NFF;

    const float* vb = vertices + (size_t)b * (NVV * 3);
    const int i0 = faces[f * 3 + 0];
    const int i1 = faces[f * 3 + 1];
    const int i2 = faces[f * 3 + 2];
    float3 v0 = loadv3(vb + (size_t)i0 * 3);
    float3 v1 = loadv3(vb + (size_t)i1 * 3);
    float3 v2 = loadv3(vb + (size_t)i2 * 3);

    const float third = 1.0f / 3.0f;
    float cx = (v0.x + v1.x + v2.x) * third;
    float cy = (v0.y + v1.y + v2.y) * third;
    float cz = (v0.z + v1.z + v2.z) * third;

    float e1x = v1.x - v0.x, e1y = v1.y - v0.y, e1z = v1.z - v0.z;
    float e2x = v2.x - v0.x, e2y = v2.y - v0.y, e2z = v2.z - v0.z;
    float nx = e1y * e2z - e1z * e2y;
    float ny = e1z * e2x - e1x * e2z;
    float nz = e1x * e2y - e1y * e2x;
    float inv = 1.0f / (sqrtf(nx * nx + ny * ny + nz * nz) + 1e-8f);
    nx *= inv; ny *= inv; nz *= inv;

    RecU r;
    r.h[0]  = (_Float16)cx;   r.h[1]  = (_Float16)cy;   r.h[2]  = (_Float16)cz;
    r.h[3]  = (_Float16)nx;   r.h[4]  = (_Float16)ny;   r.h[5]  = (_Float16)nz;
    r.h[6]  = (_Float16)v0.x; r.h[7]  = (_Float16)v0.y; r.h[8]  = (_Float16)v0.z;
    r.h[9]  = (_Float16)v1.x; r.h[10] = (_Float16)v1.y; r.h[11] = (_Float16)v1.z;
    r.h[12] = (_Float16)v2.x; r.h[13] = (_Float16)v2.y; r.h[14] = (_Float16)v2.z;
    r.h[15] = (_Float16)0.0f;

    uint4* dst = rec + (size_t)i * 2;
    dst[0] = r.u[0];
    dst[1] = r.u[1];
}

// one side: query verts (in q[9]) in cone field (c, n)
__device__ __forceinline__ float penSide(float cx, float cy, float cz,
                                         float nx, float ny, float nz,
                                         const float* q) {
    float pen = 0.0f;
#pragma unroll
    for (int v = 0; v < 3; ++v) {
        float dx = q[3 * v + 0] - cx;
        float dy = q[3 * v + 1] - cy;
        float dz = q[3 * v + 2] - cz;
        float h = dx * nx + dy * ny + dz * nz;
        float r = sqrtf(dx * dx + dy * dy + dz * dz);
        float phi = fmaxf(SIGMA - r, 0.0f);
        pen += (h < 0.0f) ? phi * h * h : 0.0f;
    }
    return pen;
}

// R4-style per-pair: loads + compute interleaved by the compiler across the
// two calls; early-out branch is uniform and (with this data) never taken.
__device__ __forceinline__ float recPen(const uint4* __restrict__ rec,
                                        int b, int f0, int f1) {
    if (f0 < 0) return 0.0f;                 // padding slot
    const int g1 = f1 < 0 ? 0 : f1;          // reference clamps with max(idx,0)
    const uint4* ra = rec + ((size_t)b * NFF + f0) * 2;
    const uint4* rb = rec + ((size_t)b * NFF + g1) * 2;
    RecU A, B;
    A.u[0] = ra[0]; A.u[1] = ra[1];
    B.u[0] = rb[0]; B.u[1] = rb[1];

    float qa[9], qb[9];
#pragma unroll
    for (int k = 0; k < 9; ++k) { qa[k] = (float)A.h[6 + k]; qb[k] = (float)B.h[6 + k]; }

    float pen = penSide((float)A.h[0], (float)A.h[1], (float)A.h[2],
                        (float)A.h[3], (float)A.h[4], (float)A.h[5], qb);
    pen      += penSide((float)B.h[0], (float)B.h[1], (float)B.h[2],
                        (float)B.h[3], (float)B.h[4], (float)B.h[5], qa);
    return pen;
}

// ---------------- phase 2: 2 pairs/thread, per-WAVE partials (no barrier) ----
__global__ __launch_bounds__(256) void pair_kernel(
    const uint4* __restrict__ rec,        // [B*NF][2]
    const int*   __restrict__ cidx,       // [B, NC, 2]
    float*       __restrict__ partials)   // [NPART]
{
    const int b    = blockIdx.x;          // batch -> XCD b%8
    const int slot = blockIdx.y;
    const int base = slot * PAIRS_PER_BLOCK + threadIdx.x * 2;   // pairs {base, base+1}
    float pen = 0.0f;

    if (base < NCC) {                     // NCC even, base even -> covers base+1
        const v4i* c4 = (const v4i*)(cidx + (size_t)b * NCC * 2)
                        + ((size_t)slot * 256 + threadIdx.x);
        v4i pr = __builtin_nontemporal_load(c4);   // {r0,i0,r1,i1}
        pen = recPen(rec, b, pr.x, pr.y) + recPen(rec, b, pr.z, pr.w);
    }

    // wave (64-lane) shuffle reduce; lane 0 of each wave writes its partial.
    // No LDS, no __syncthreads -> waves retire independently.
#pragma unroll
    for (int off = 32; off > 0; off >>= 1)
        pen += __shfl_down(pen, off, 64);

    const int lane = threadIdx.x & 63;
    const int wv   = threadIdx.x >> 6;
    if (lane == 0)
        partials[(((size_t)b * SLOTS2 + slot) << 2) + wv] = pen;
}

// ---------------- phase 3: fold partials, apply weight/B ----------------
__global__ __launch_bounds__(1024) void reduce_kernel(
    const float* __restrict__ partials,
    const float* __restrict__ weight,
    float*       __restrict__ out)
{
    float s = 0.0f;
    for (int i = threadIdx.x; i < NPART; i += 1024)
        s += partials[i];
#pragma unroll
    for (int off = 32; off > 0; off >>= 1)
        s += __shfl_down(s, off, 64);

    __shared__ float smem[16];
    const int lane = threadIdx.x & 63;
    const int wv   = threadIdx.x >> 6;
    if (lane == 0) smem[wv] = s;
    __syncthreads();
    if (threadIdx.x == 0) {
        float t = 0.0f;
#pragma unroll
        for (int w = 0; w < 16; ++w) t += smem[w];
        out[0] = t * weight[0] * (1.0f / (float)BB);
    }
}

// ---------------- fallback: direct per-pair with atomics (tiny ws) --------
__global__ void init_kernel(float* __restrict__ accum) { accum[0] = 0.0f; }

__device__ __forceinline__ float conePen(float3 a0, float3 a1, float3 a2,
                                         float3 q0, float3 q1, float3 q2) {
    const float third = 1.0f / 3.0f;
    float cx = (a0.x + a1.x + a2.x) * third;
    float cy = (a0.y + a1.y + a2.y) * third;
    float cz = (a0.z + a1.z + a2.z) * third;
    float e1x = a1.x - a0.x, e1y = a1.y - a0.y, e1z = a1.z - a0.z;
    float e2x = a2.x - a0.x, e2y = a2.y - a0.y, e2z = a2.z - a0.z;
    float nx = e1y * e2z - e1z * e2y;
    float ny = e1z * e2x - e1x * e2z;
    float nz = e1x * e2y - e1y * e2x;
    float inv = 1.0f / (sqrtf(nx * nx + ny * ny + nz * nz) + 1e-8f);
    nx *= inv; ny *= inv; nz *= inv;
    float3 q[3] = {q0, q1, q2};
    float pen = 0.0f;
#pragma unroll
    for (int v = 0; v < 3; ++v) {
        float dx = q[v].x - cx, dy = q[v].y - cy, dz = q[v].z - cz;
        float h = dx * nx + dy * ny + dz * nz;
        float r = sqrtf(dx * dx + dy * dy + dz * dz);
        float phi = fmaxf(SIGMA - r, 0.0f);
        pen += (h < 0.0f) ? phi * h * h : 0.0f;
    }
    return pen;
}

__global__ __launch_bounds__(256) void pen_direct(
    const float* __restrict__ vertices, const int* __restrict__ faces,
    const int2* __restrict__ cidx, float* __restrict__ accum)
{
    const int i = blockIdx.x * blockDim.x + threadIdx.x;
    float pen = 0.0f;
    if (i < BB * NCC) {
        const int b = i / NCC;
        const int2 pr = cidx[i];
        if (pr.x >= 0) {
            const int f0 = pr.x;
            const int f1 = pr.y < 0 ? 0 : pr.y;
            const float* vb = vertices + (size_t)b * (NVV * 3);
            float3 a0 = loadv3(vb + (size_t)faces[f0*3+0] * 3);
            float3 a1 = loadv3(vb + (size_t)faces[f0*3+1] * 3);
            float3 a2 = loadv3(vb + (size_t)faces[f0*3+2] * 3);
            float3 b0 = loadv3(vb + (size_t)faces[f1*3+0] * 3);
            float3 b1 = loadv3(vb + (size_t)faces[f1*3+1] * 3);
            float3 b2 = loadv3(vb + (size_t)faces[f1*3+2] * 3);
            pen = conePen(a0,a1,a2,b0,b1,b2) + conePen(b0,b1,b2,a0,a1,a2);
        }
    }
#pragma unroll
    for (int off = 32; off > 0; off >>= 1)
        pen += __shfl_down(pen, off, 64);
    __shared__ float smem[4];
    const int lane = threadIdx.x & 63;
    const int wv   = threadIdx.x >> 6;
    if (lane == 0) smem[wv] = pen;
    __syncthreads();
    if (threadIdx.x == 0)
        atomicAdd(accum, smem[0] + smem[1] + smem[2] + smem[3]);
}

__global__ void fin_kernel(const float* __restrict__ accum,
                           const float* __restrict__ weight,
                           float* __restrict__ out)
{
    out[0] = accum[0] * weight[0] * (1.0f / (float)BB);
}

extern "C" void kernel_launch(void* const* d_in, const int* in_sizes, int n_in,
                              void* d_out, int out_size, void* d_ws, size_t ws_size,
                              hipStream_t stream) {
    const float* vertices = (const float*)d_in[4];
    const float* weight   = (const float*)d_in[5];
    const int*   faces    = (const int*)d_in[6];
    const int*   cidx     = (const int*)d_in[7];
    float* out = (float*)d_out;

    if (ws_size >= REC_BYTES + NPART * sizeof(float) + 256) {
        uint4* rec      = (uint4*)d_ws;
        float* partials = (float*)((char*)d_ws + REC_BYTES);

        const int totalFaces = BB * NFF;             // 440,832
        face_kernel<<<dim3((totalFaces + 255) / 256), dim3(256), 0, stream>>>(
            vertices, faces, rec);
        pair_kernel<<<dim3(BB, SLOTS2), dim3(256), 0, stream>>>(rec, cidx, partials);
        reduce_kernel<<<dim3(1), dim3(1024), 0, stream>>>(partials, weight, out);
    } else {
        float* accum = (float*)d_ws;
        const int totalPairs = BB * NCC;
        init_kernel<<<dim3(1), dim3(1), 0, stream>>>(accum);
        pen_direct<<<dim3((totalPairs + 255) / 256), dim3(256), 0, stream>>>(
            vertices, faces, (const int2*)cidx, accum);
        fin_kernel<<<dim3(1), dim3(1), 0, stream>>>(accum, weight, out);
    }
}